// Round 10
// baseline (190.300 us; speedup 1.0000x reference)
//
#include <hip/hip_runtime.h>
#include <hip/hip_bf16.h>

// MultiHeadAttention fused pipeline. FP32 in/out, bf16 MFMA compute, fp32 accum.
// B=2 T=2048 C=1024 H=16 D=64.
// Stage 0: convert x -> bf16 row-major; W* -> bf16 SHUFFLED fragment-major
//          (flatmm-style) so a wave's B-fragment load is one coalesced 1KB burst.
// Stage 1: QKV GEMM (round-9 proven, 47.7us): 128x128 tile BK=64, A via
//          global_load_lds + XOR-8 swizzle, B streamed coalesced; RoPE +
//          exp2-folded softmax scale (0.125*log2e) fused in epilogue.
// Stage 2: attention: paired q-tiles (qlo=p, qhi=31-p -> uniform 33 chunks),
//          128 KEYS PER STAGING ROUND (halves barrier drains), hi/lo share
//          all K/V fragment reads, no-max softmax via exp2, l via ones-MFMA,
//          per-wave P LDS round trip, XCD-swizzled bh.
// Stage 3: out GEMM 128x64, A LDS-staged, B=Wo shuffled-streamed -> fp32 d_out.
//
// MFMA layouts (HW-verified): A[m=lane&15][k=quad*8+j]; B[n=lane&15][k=quad*8+j];
// C/D: row=quad*4+reg, col=lane&15.
// LDS swizzle: 16B chunk (row, ch) stored at row*8 + (ch ^ (row&7)).

typedef __hip_bfloat16 bf16;
typedef __attribute__((ext_vector_type(8))) short bf16x8;
typedef __attribute__((ext_vector_type(4))) float f32x4;
typedef __attribute__((ext_vector_type(4))) short short4v;

#define MFMA16(a, b, c) __builtin_amdgcn_mfma_f32_16x16x32_bf16((a), (b), (c), 0, 0, 0)

constexpr int Bn = 2, Hn = 16, Tn = 2048, Dn = 64, Cn = 1024;
constexpr size_t NE = (size_t)Bn * Tn * Cn;   // 4,194,304
constexpr size_t WE = (size_t)Cn * Cn;        // 1,048,576
// softmax scale 1/8 folded with log2(e) so p = exp2(s) == exp(s/8 * d)
constexpr float QSCALE = 0.125f * 1.44269504088896f;

__device__ inline unsigned short bfbits(float x) {
    bf16 b = __float2bfloat16(x);
    return *(unsigned short*)&b;
}

__device__ inline bf16x8 pack8(f32x4 a, f32x4 b) {
    bf16x8 r;
#pragma unroll
    for (int i = 0; i < 4; ++i) r[i] = (short)bfbits(a[i]);
#pragma unroll
    for (int i = 0; i < 4; ++i) r[4 + i] = (short)bfbits(b[i]);
    return r;
}

__device__ inline void gl_lds16(const bf16* g, unsigned short* l) {
    __builtin_amdgcn_global_load_lds(
        (const __attribute__((address_space(1))) void*)g,
        (__attribute__((address_space(3))) void*)l, 16, 0, 0);
}

// stage a 128-row x 64-col bf16 tile (1024 16B-chunks) swizzled; ld = row stride
__device__ inline void stage128(const bf16* gbase, int ld, unsigned short* lds,
                                int wave, int lane) {
#pragma unroll
    for (int j = 0; j < 4; ++j) {
        int p = j * 256 + wave * 64 + lane;
        int row = p >> 3, ch = (p & 7) ^ (row & 7);
        gl_lds16(gbase + (size_t)row * ld + ch * 8,
                 lds + (size_t)(j * 256 + wave * 64) * 8);
    }
}
// stage a 64x64 tile (512 chunks)
__device__ inline void stage64(const bf16* gbase, int ld, unsigned short* lds,
                               int wave, int lane) {
#pragma unroll
    for (int j = 0; j < 2; ++j) {
        int p = j * 256 + wave * 64 + lane;
        int row = p >> 3, ch = (p & 7) ^ (row & 7);
        gl_lds16(gbase + (size_t)row * ld + ch * 8,
                 lds + (size_t)(j * 256 + wave * 64) * 8);
    }
}

__device__ inline bf16x8 ldsfrag(const unsigned short* base, int row, int ch) {
    return *(const bf16x8*)&base[row * 64 + ((ch ^ (row & 7)) * 8)];
}

// ---------------------------------------------------------------- convert
// blocks [0,2048): x rows (row-major bf16). [2048,4096): W shuffled fragments:
// frag f=(n>>4)*32+(k>>5), elem f*512 + lane*8, lane=((k>>3)&3)*16+(n&15).
__global__ __launch_bounds__(256) void convert_kernel(
    const float* __restrict__ x, const float* __restrict__ wq,
    const float* __restrict__ wk, const float* __restrict__ wv,
    const float* __restrict__ wo, bf16* __restrict__ dst)
{
    int blk = blockIdx.x;
    if (blk < 2048) {
        const float* src = x + (size_t)blk * 2048;
        int t = threadIdx.x * 8;
        f32x4 a = *(const f32x4*)(src + t);
        f32x4 b2 = *(const f32x4*)(src + t + 4);
        *(bf16x8*)(dst + (size_t)blk * 2048 + t) = pack8(a, b2);
    } else {
        int w = (blk - 2048) >> 9, b = (blk - 2048) & 511;
        const float* s4[4] = {wq, wk, wv, wo};
        const float* W = s4[w];
        int frag = b * 4 + (threadIdx.x >> 6);     // 0..2047
        int lane = threadIdx.x & 63;
        int lx = lane & 15, quad = lane >> 4;
        int nb = frag >> 5, kc = frag & 31;
        const float* src = W + (size_t)(nb * 16 + lx) * Cn + kc * 32 + quad * 8;
        f32x4 a = *(const f32x4*)(src);
        f32x4 b2 = *(const f32x4*)(src + 4);
        *(bf16x8*)(dst + NE + (size_t)w * WE + (size_t)frag * 512 + lane * 8) =
            pack8(a, b2);
    }
}

// ---------------------------------------------------------------- QKV GEMM
// 128x128 tile, BK=64, 4 waves (2x2), wave 64x64 (4x4 accs).
// A via LDS; B streamed coalesced from shuffled weights (1KB burst per frag).
__global__ __launch_bounds__(256) void gemm_qkv_kernel(
    const bf16* __restrict__ X, const bf16* __restrict__ Wbase,
    bf16* __restrict__ Qo, bf16* __restrict__ Ko, bf16* __restrict__ Vo)
{
    __shared__ unsigned short As[128 * 64];
    const int bm = blockIdx.x, bn = blockIdx.y, wsel = blockIdx.z;
    const bf16* W = Wbase + (size_t)wsel * WE;
    const int tid  = threadIdx.x;
    const int wave = tid >> 6, lane = tid & 63;
    const int lx   = lane & 15, quad = lane >> 4;
    const int wm = wave >> 1, wn = wave & 1;

    const bf16* abase = X + (size_t)(bm * 128) * Cn;
    const int nb0 = bn * 8 + wn * 4;               // first 16-row n-tile of wave
    const bf16* wfrag = W + (size_t)nb0 * 32 * 512 + (size_t)lane * 8;

    f32x4 acc[4][4] = {};   // [mt][nt]
    for (int kt = 0; kt < Cn / 64; ++kt) {
        __syncthreads();
        stage128(abase + kt * 64, Cn, As, wave, lane);
        bf16x8 bfv[4][2];   // coalesced B frags, loaded while A staging flies
#pragma unroll
        for (int nt = 0; nt < 4; ++nt)
#pragma unroll
            for (int ks = 0; ks < 2; ++ks)
                bfv[nt][ks] = *(const bf16x8*)(wfrag +
                    ((size_t)nt * 32 + kt * 2 + ks) * 512);
        __syncthreads();
#pragma unroll
        for (int ks = 0; ks < 2; ++ks) {
            bf16x8 af[4];
#pragma unroll
            for (int mt = 0; mt < 4; ++mt)
                af[mt] = ldsfrag(As, wm * 64 + mt * 16 + lx, ks * 4 + quad);
#pragma unroll
            for (int mt = 0; mt < 4; ++mt)
#pragma unroll
                for (int nt = 0; nt < 4; ++nt)
                    acc[mt][nt] = MFMA16(af[mt], bfv[nt][ks], acc[mt][nt]);
        }
    }

    const int h = bn * 2 + wn;   // 64-col wave block == one head
    if (wsel <= 1) {             // fused RoPE: pair (d, d+32) = (nt, nt+2)
#pragma unroll
        for (int mt = 0; mt < 4; ++mt)
#pragma unroll
            for (int r = 0; r < 4; ++r) {
                int mg = bm * 128 + wm * 64 + mt * 16 + quad * 4 + r;
                int t  = mg & (Tn - 1);
#pragma unroll
                for (int nt = 0; nt < 2; ++nt) {
                    int d = nt * 16 + lx;   // 0..31
                    float ang = (float)t * __expf(-(float)d * 0.2878231366f);
                    float c, s;
                    __sincosf(ang, &s, &c);
                    float a0 = acc[mt][nt][r], a1 = acc[mt][nt + 2][r];
                    acc[mt][nt][r]     = a0 * c - a1 * s;
                    acc[mt][nt + 2][r] = a1 * c + a0 * s;
                }
            }
    }

#pragma unroll
    for (int mt = 0; mt < 4; ++mt) {
        int mg0 = bm * 128 + wm * 64 + mt * 16 + quad * 4;
        int b = mg0 >> 11, t0 = mg0 & (Tn - 1);
        if (wsel == 0) {        // Q: exp2-folded softmax scale
#pragma unroll
            for (int nt = 0; nt < 4; ++nt)
#pragma unroll
                for (int r = 0; r < 4; ++r) {
                    int d = nt * 16 + lx;
                    Qo[((size_t)(b * Hn + h) * Tn + t0 + r) * Dn + d] =
                        __float2bfloat16(acc[mt][nt][r] * QSCALE);
                }
        } else if (wsel == 1) { // K
#pragma unroll
            for (int nt = 0; nt < 4; ++nt)
#pragma unroll
                for (int r = 0; r < 4; ++r) {
                    int d = nt * 16 + lx;
                    Ko[((size_t)(b * Hn + h) * Tn + t0 + r) * Dn + d] =
                        __float2bfloat16(acc[mt][nt][r]);
                }
        } else {                // V^T [B,H,D,T]: r-contiguous -> 8B store
#pragma unroll
            for (int nt = 0; nt < 4; ++nt) {
                int d = nt * 16 + lx;
                short4v pk;
#pragma unroll
                for (int r = 0; r < 4; ++r) pk[r] = (short)bfbits(acc[mt][nt][r]);
                *(short4v*)&Vo[((size_t)(b * Hn + h) * Dn + d) * Tn + t0] = pk;
            }
        }
    }
}

// ---------------------------------------------------------------- out GEMM
// 128x64 tile (grid 32x16 = 512 blocks), BK=64, 4 waves 2x2, wave 64x32.
// A via LDS; B = Wo streamed coalesced from shuffled layout.
__global__ __launch_bounds__(256) void gemm_out_kernel(
    const bf16* __restrict__ A, const bf16* __restrict__ W, float* __restrict__ Out)
{
    __shared__ unsigned short As[128 * 64];
    const int bm = blockIdx.x, bn = blockIdx.y;
    const int tid  = threadIdx.x;
    const int wave = tid >> 6, lane = tid & 63;
    const int lx   = lane & 15, quad = lane >> 4;
    const int wm = wave >> 1, wn = wave & 1;

    const bf16* abase = A + (size_t)(bm * 128) * Cn;
    const int nb0 = bn * 4 + wn * 2;
    const bf16* wfrag = W + (size_t)nb0 * 32 * 512 + (size_t)lane * 8;

    f32x4 acc[4][2] = {};
    for (int kt = 0; kt < Cn / 64; ++kt) {
        __syncthreads();
        stage128(abase + kt * 64, Cn, As, wave, lane);
        bf16x8 bfv[2][2];
#pragma unroll
        for (int nt = 0; nt < 2; ++nt)
#pragma unroll
            for (int ks = 0; ks < 2; ++ks)
                bfv[nt][ks] = *(const bf16x8*)(wfrag +
                    ((size_t)nt * 32 + kt * 2 + ks) * 512);
        __syncthreads();
#pragma unroll
        for (int ks = 0; ks < 2; ++ks) {
            bf16x8 af[4];
#pragma unroll
            for (int mt = 0; mt < 4; ++mt)
                af[mt] = ldsfrag(As, wm * 64 + mt * 16 + lx, ks * 4 + quad);
#pragma unroll
            for (int mt = 0; mt < 4; ++mt)
#pragma unroll
                for (int nt = 0; nt < 2; ++nt)
                    acc[mt][nt] = MFMA16(af[mt], bfv[nt][ks], acc[mt][nt]);
        }
    }
#pragma unroll
    for (int mt = 0; mt < 4; ++mt)
#pragma unroll
        for (int nt = 0; nt < 2; ++nt)
#pragma unroll
            for (int r = 0; r < 4; ++r) {
                int mg = bm * 128 + wm * 64 + mt * 16 + quad * 4 + r;
                int ng = bn * 64 + wn * 32 + nt * 16 + lx;
                Out[(size_t)mg * Cn + ng] = acc[mt][nt][r];
            }
}

// ---------------------------------------------------------------- Attention
// 512 blocks: f = xcd + 8*pair + 128*bh_local; bh = xcd*4 + bh_local.
// Block handles q-tiles qhi=31-pair (always) and qlo=pair -> uniform 33 chunks.
// 128 keys staged per barrier round (two 64-key buffers); hi/lo share all K/V
// fragment reads. p = exp2(s) (scale pre-folded into Q), l via ones-MFMA.
__device__ inline void attn_chunk(
    const unsigned short* Ks, const unsigned short* Vs,
    unsigned short* phi, unsigned short* plo,
    bf16x8 aqhi0, bf16x8 aqhi1, bf16x8 aqlo0, bf16x8 aqlo1, bf16x8 ones,
    f32x4 (&acc_o)[2][4], f32x4 (&acc_l)[2],
    int row_local, bool mask_hi, bool do_lo, bool mask_lo, int lx, int quad)
{
    f32x4 shi[4] = {}, slo[4] = {};
#pragma unroll
    for (int nt = 0; nt < 4; ++nt) {
        int key = nt * 16 + lx;
        bf16x8 k0 = ldsfrag(Ks, key, quad);
        bf16x8 k1 = ldsfrag(Ks, key, quad + 4);
        shi[nt] = MFMA16(aqhi0, k0, shi[nt]);
        shi[nt] = MFMA16(aqhi1, k1, shi[nt]);
        if (do_lo) {
            slo[nt] = MFMA16(aqlo0, k0, slo[nt]);
            slo[nt] = MFMA16(aqlo1, k1, slo[nt]);
        }
    }
    if (!mask_hi) {
#pragma unroll
        for (int nt = 0; nt < 4; ++nt)
#pragma unroll
            for (int r = 0; r < 4; ++r)
                phi[(quad * 4 + r) * 72 + nt * 16 + lx] = bfbits(exp2f(shi[nt][r]));
    } else {
#pragma unroll
        for (int nt = 0; nt < 4; ++nt) {
            int keyl = nt * 16 + lx;
#pragma unroll
            for (int r = 0; r < 4; ++r) {
                float p = (keyl > row_local + r) ? 0.0f : exp2f(shi[nt][r]);
                phi[(quad * 4 + r) * 72 + nt * 16 + lx] = bfbits(p);
            }
        }
    }
    if (do_lo) {
        if (!mask_lo) {
#pragma unroll
            for (int nt = 0; nt < 4; ++nt)
#pragma unroll
                for (int r = 0; r < 4; ++r)
                    plo[(quad * 4 + r) * 72 + nt * 16 + lx] = bfbits(exp2f(slo[nt][r]));
        } else {
#pragma unroll
            for (int nt = 0; nt < 4; ++nt) {
                int keyl = nt * 16 + lx;
#pragma unroll
                for (int r = 0; r < 4; ++r) {
                    float p = (keyl > row_local + r) ? 0.0f : exp2f(slo[nt][r]);
                    plo[(quad * 4 + r) * 72 + nt * 16 + lx] = bfbits(p);
                }
            }
        }
    }
    asm volatile("s_waitcnt lgkmcnt(0)" ::: "memory");
    bf16x8 aph0 = *(const bf16x8*)&phi[lx * 72 + quad * 8];
    bf16x8 aph1 = *(const bf16x8*)&phi[lx * 72 + 32 + quad * 8];
    acc_l[0] = MFMA16(aph0, ones, acc_l[0]);
    acc_l[0] = MFMA16(aph1, ones, acc_l[0]);
    bf16x8 apl0, apl1;
    if (do_lo) {
        apl0 = *(const bf16x8*)&plo[lx * 72 + quad * 8];
        apl1 = *(const bf16x8*)&plo[lx * 72 + 32 + quad * 8];
        acc_l[1] = MFMA16(apl0, ones, acc_l[1]);
        acc_l[1] = MFMA16(apl1, ones, acc_l[1]);
    }
#pragma unroll
    for (int dt = 0; dt < 4; ++dt) {
        int d = dt * 16 + lx;
        bf16x8 v0 = ldsfrag(Vs, d, quad);
        bf16x8 v1 = ldsfrag(Vs, d, quad + 4);
        acc_o[0][dt] = MFMA16(aph0, v0, acc_o[0][dt]);
        acc_o[0][dt] = MFMA16(aph1, v1, acc_o[0][dt]);
        if (do_lo) {
            acc_o[1][dt] = MFMA16(apl0, v0, acc_o[1][dt]);
            acc_o[1][dt] = MFMA16(apl1, v1, acc_o[1][dt]);
        }
    }
}

__global__ __launch_bounds__(256) void attn_kernel(
    const bf16* __restrict__ Q, const bf16* __restrict__ K,
    const bf16* __restrict__ Vt, bf16* __restrict__ O)
{
    __shared__ unsigned short Ks[2][64 * 64];
    __shared__ unsigned short Vs[2][64 * 64];
    __shared__ unsigned short Pl[2][4][16 * 72];
    const int f = blockIdx.x;
    const int bh   = (f & 7) * 4 + (f >> 7);
    const int pair = (f >> 3) & 15;
    const int qlo = pair, qhi = 31 - pair;
    const int tid  = threadIdx.x;
    const int wave = tid >> 6, lane = tid & 63;
    const int lx   = lane & 15, quad = lane >> 4;

    const bf16* Qh = Q  + (size_t)bh * Tn * Dn;
    const bf16* Kh = K  + (size_t)bh * Tn * Dn;
    const bf16* Vh = Vt + (size_t)bh * Dn * Tn;
    unsigned short* phi = &Pl[0][wave][0];
    unsigned short* plo = &Pl[1][wave][0];

    const int rlo = qlo * 64 + wave * 16 + lx;
    const int rhi = qhi * 64 + wave * 16 + lx;
    bf16x8 aqlo0 = *(const bf16x8*)(Qh + (size_t)rlo * Dn + quad * 8);
    bf16x8 aqlo1 = *(const bf16x8*)(Qh + (size_t)rlo * Dn + 32 + quad * 8);
    bf16x8 aqhi0 = *(const bf16x8*)(Qh + (size_t)rhi * Dn + quad * 8);
    bf16x8 aqhi1 = *(const bf16x8*)(Qh + (size_t)rhi * Dn + 32 + quad * 8);

    bf16x8 ones;
#pragma unroll
    for (int i = 0; i < 8; ++i) ones[i] = (short)0x3F80;

    f32x4 acc_o[2][4] = {};   // [0]=hi tile, [1]=lo tile
    f32x4 acc_l[2] = {};
    const int row_local = wave * 16 + quad * 4;

    for (int c = 0; c <= qhi; c += 2) {
        const bool two = (c + 1 <= qhi);   // block-uniform
        __syncthreads();
        stage64(Kh + (size_t)c * 64 * Dn, Dn, Ks[0], wave, lane);
        stage64(Vh + (size_t)c * 64, Tn, Vs[0], wave, lane);
        if (two) {
            stage64(Kh + (size_t)(c + 1) * 64 * Dn, Dn, Ks[1], wave, lane);
            stage64(Vh + (size_t)(c + 1) * 64, Tn, Vs[1], wave, lane);
        }
        __syncthreads();
        attn_chunk(Ks[0], Vs[0], phi, plo, aqhi0, aqhi1, aqlo0, aqlo1, ones,
                   acc_o, acc_l, row_local,
                   c == qhi, c <= qlo, c == qlo, lx, quad);
        if (two)
            attn_chunk(Ks[1], Vs[1], phi, plo, aqhi0, aqhi1, aqlo0, aqlo1, ones,
                       acc_o, acc_l, row_local,
                       c + 1 == qhi, c + 1 <= qlo, c + 1 == qlo, lx, quad);
    }

    // epilogue: O[b,t,h,d] (= [B,T,C] row-major), bf16
    const int b = bh >> 4, h = bh & 15;
#pragma unroll
    for (int tile = 0; tile < 2; ++tile) {
        int qb = tile ? qlo : qhi;
#pragma unroll
        for (int dt = 0; dt < 4; ++dt)
#pragma unroll
            for (int r = 0; r < 4; ++r) {
                int t = qb * 64 + wave * 16 + quad * 4 + r;
                int d = dt * 16 + lx;
                float o = acc_o[tile][dt][r] / acc_l[tile][r];
                O[((size_t)(b * Tn + t) * Hn + h) * Dn + d] = __float2bfloat16(o);
            }
    }
}

// ---------------------------------------------------------------- launch
extern "C" void kernel_launch(void* const* d_in, const int* in_sizes, int n_in,
                              void* d_out, int out_size, void* d_ws, size_t ws_size,
                              hipStream_t stream)
{
    const float* x  = (const float*)d_in[0];
    const float* Wq = (const float*)d_in[1];
    const float* Wk = (const float*)d_in[2];
    const float* Wv = (const float*)d_in[3];
    const float* Wo = (const float*)d_in[4];
    float* out = (float*)d_out;

    bf16* ws = (bf16*)d_ws;
    bf16* Xb = ws;                    // [B,T,C] bf16 (aliased by Ab after QKV)
    bf16* Wb = ws + NE;               // Wq,Wk,Wv,Wo bf16 SHUFFLED, contiguous
    bf16* Qb = ws + NE + 4 * WE;      // [B,H,T,D] (pre-scaled by 0.125*log2e)
    bf16* Kb = Qb + NE;               // [B,H,T,D]
    bf16* Vb = Kb + NE;               // [B,H,D,T]
    bf16* Ab = Xb;                    // attention out, reuses Xb (dead after QKV)

    convert_kernel<<<4096, 256, 0, stream>>>(x, Wq, Wk, Wv, Wo, ws);
    gemm_qkv_kernel<<<dim3(32, 8, 3), 256, 0, stream>>>(Xb, Wb, Qb, Kb, Vb);
    attn_kernel<<<512, 256, 0, stream>>>(Qb, Kb, Vb, Ab);
    gemm_out_kernel<<<dim3(32, 16), 256, 0, stream>>>(Ab, Wb + 3 * WE, out);
}

// Round 11
// 177.164 us; speedup vs baseline: 1.0741x; 1.0741x over previous
//
#include <hip/hip_runtime.h>
#include <hip/hip_bf16.h>

// MultiHeadAttention fused pipeline. FP32 in/out, bf16 MFMA compute, fp32 accum.
// B=2 T=2048 C=1024 H=16 D=64.
// Stage 0: convert x AND W* -> bf16 in SHUFFLED fragment-major layout
//          (frag f = (row>>4)*32 + (k>>5); elem f*512 + lane*8,
//           lane = ((k>>3)&3)*16 + (row&15)) -> a wave's MFMA fragment load
//          is ONE coalesced 1KB burst.
// Stage 1: QKV GEMM with ZERO LDS / ZERO BARRIERS: both A (x) and B (W)
//          fragments streamed global->VGPR with cur/next prefetch; 16 MFMA
//          per 32-k step. No vmcnt(0) barrier drains (the measured 80% stall
//          of the 2-barrier structure). RoPE + exp2-folded scale in epilogue.
// Stage 2: attention (round-9/7 proven): one 64-row q-tile per block,
//          1024 blocks, longest-first, XCD-swizzled bh, K/V LDS-staged,
//          no-max softmax via exp2 (scale pre-folded), l via ones-MFMA.
// Stage 3: out GEMM 128x64 (round-9 proven): A LDS-staged row-major,
//          B=Wo shuffled-streamed -> fp32 d_out.
//
// MFMA layouts (HW-verified): A[m=lane&15][k=quad*8+j]; B[n=lane&15][k=quad*8+j];
// C/D: row=quad*4+reg, col=lane&15.
// LDS swizzle (attn/out staging): 16B chunk (row, ch) at row*8 + (ch^(row&7)).

typedef __hip_bfloat16 bf16;
typedef __attribute__((ext_vector_type(8))) short bf16x8;
typedef __attribute__((ext_vector_type(4))) float f32x4;
typedef __attribute__((ext_vector_type(4))) short short4v;

#define MFMA16(a, b, c) __builtin_amdgcn_mfma_f32_16x16x32_bf16((a), (b), (c), 0, 0, 0)

constexpr int Bn = 2, Hn = 16, Tn = 2048, Dn = 64, Cn = 1024;
constexpr size_t NE = (size_t)Bn * Tn * Cn;   // 4,194,304
constexpr size_t WE = (size_t)Cn * Cn;        // 1,048,576
// softmax scale 1/8 folded with log2(e): p = exp2(s) == exp(dot/8)
constexpr float QSCALE = 0.125f * 1.44269504088896f;

__device__ inline unsigned short bfbits(float x) {
    bf16 b = __float2bfloat16(x);
    return *(unsigned short*)&b;
}

__device__ inline bf16x8 pack8(f32x4 a, f32x4 b) {
    bf16x8 r;
#pragma unroll
    for (int i = 0; i < 4; ++i) r[i] = (short)bfbits(a[i]);
#pragma unroll
    for (int i = 0; i < 4; ++i) r[4 + i] = (short)bfbits(b[i]);
    return r;
}

__device__ inline void gl_lds16(const bf16* g, unsigned short* l) {
    __builtin_amdgcn_global_load_lds(
        (const __attribute__((address_space(1))) void*)g,
        (__attribute__((address_space(3))) void*)l, 16, 0, 0);
}

// stage a 128-row x 64-col bf16 tile (1024 16B-chunks) swizzled; ld = row stride
__device__ inline void stage128(const bf16* gbase, int ld, unsigned short* lds,
                                int wave, int lane) {
#pragma unroll
    for (int j = 0; j < 4; ++j) {
        int p = j * 256 + wave * 64 + lane;
        int row = p >> 3, ch = (p & 7) ^ (row & 7);
        gl_lds16(gbase + (size_t)row * ld + ch * 8,
                 lds + (size_t)(j * 256 + wave * 64) * 8);
    }
}
// stage a 64x64 tile (512 chunks)
__device__ inline void stage64(const bf16* gbase, int ld, unsigned short* lds,
                               int wave, int lane) {
#pragma unroll
    for (int j = 0; j < 2; ++j) {
        int p = j * 256 + wave * 64 + lane;
        int row = p >> 3, ch = (p & 7) ^ (row & 7);
        gl_lds16(gbase + (size_t)row * ld + ch * 8,
                 lds + (size_t)(j * 256 + wave * 64) * 8);
    }
}

__device__ inline bf16x8 ldsfrag(const unsigned short* base, int row, int ch) {
    return *(const bf16x8*)&base[row * 64 + ((ch ^ (row & 7)) * 8)];
}

// ---------------------------------------------------------------- convert
// blocks [0,2048): x -> fragment-major (256 m-tiles x 32 k-chunks).
// blocks [2048,4096): W* -> fragment-major (64 n-tiles x 32 k-chunks each).
// Both use the same shuffle: src row = tile*16 + lx, col = kc*32 + quad*8.
__global__ __launch_bounds__(256) void convert_kernel(
    const float* __restrict__ x, const float* __restrict__ wq,
    const float* __restrict__ wk, const float* __restrict__ wv,
    const float* __restrict__ wo, bf16* __restrict__ dst)
{
    int blk = blockIdx.x;
    int lane = threadIdx.x & 63;
    int lx = lane & 15, quad = lane >> 4;
    const float* src;
    size_t doff;
    if (blk < 2048) {
        int frag = blk * 4 + (threadIdx.x >> 6);   // 0..8191
        int mt = frag >> 5, kc = frag & 31;
        src = x + (size_t)(mt * 16 + lx) * Cn + kc * 32 + quad * 8;
        doff = (size_t)frag * 512 + lane * 8;
    } else {
        int w = (blk - 2048) >> 9, b = (blk - 2048) & 511;
        const float* s4[4] = {wq, wk, wv, wo};
        int frag = b * 4 + (threadIdx.x >> 6);     // 0..2047
        int nb = frag >> 5, kc = frag & 31;
        src = s4[w] + (size_t)(nb * 16 + lx) * Cn + kc * 32 + quad * 8;
        doff = NE + (size_t)w * WE + (size_t)frag * 512 + lane * 8;
    }
    f32x4 a = *(const f32x4*)(src);
    f32x4 b2 = *(const f32x4*)(src + 4);
    *(bf16x8*)(dst + doff) = pack8(a, b2);
}

// ---------------------------------------------------------------- QKV GEMM
// ZERO-LDS streaming GEMM: 4 waves (2x2), wave 64x64 (4x4 accs), K-step 32.
// All fragment loads are coalesced 1KB bursts from fragment-major buffers.
// No __syncthreads in the K-loop -> no barrier drains.
__global__ __launch_bounds__(256) void gemm_qkv_kernel(
    const bf16* __restrict__ Xf, const bf16* __restrict__ Wbase,
    bf16* __restrict__ Qo, bf16* __restrict__ Ko, bf16* __restrict__ Vo)
{
    const int bm = blockIdx.x, bn = blockIdx.y, wsel = blockIdx.z;
    const bf16* W = Wbase + (size_t)wsel * WE;
    const int tid  = threadIdx.x;
    const int wave = tid >> 6, lane = tid & 63;
    const int lx   = lane & 15, quad = lane >> 4;
    const int wm = wave >> 1, wn = wave & 1;

    const int mt0 = bm * 8 + wm * 4;               // first 16-row m-tile
    const int nb0 = bn * 8 + wn * 4;               // first 16-row n-tile
    const bf16* afrag = Xf + (size_t)mt0 * 32 * 512 + (size_t)lane * 8;
    const bf16* wfrag = W + (size_t)nb0 * 32 * 512 + (size_t)lane * 8;

    f32x4 acc[4][4] = {};   // [mt][nt]
    bf16x8 acur[4], bcur[4], anxt[4], bnxt[4];
#pragma unroll
    for (int i = 0; i < 4; ++i) {
        acur[i] = *(const bf16x8*)(afrag + (size_t)i * 32 * 512);
        bcur[i] = *(const bf16x8*)(wfrag + (size_t)i * 32 * 512);
    }
    for (int kc = 0; kc < 32; ++kc) {
        if (kc < 31) {   // prefetch next k-chunk while current MFMAs run
#pragma unroll
            for (int i = 0; i < 4; ++i) {
                anxt[i] = *(const bf16x8*)(afrag + ((size_t)i * 32 + kc + 1) * 512);
                bnxt[i] = *(const bf16x8*)(wfrag + ((size_t)i * 32 + kc + 1) * 512);
            }
        }
#pragma unroll
        for (int mt = 0; mt < 4; ++mt)
#pragma unroll
            for (int nt = 0; nt < 4; ++nt)
                acc[mt][nt] = MFMA16(acur[mt], bcur[nt], acc[mt][nt]);
#pragma unroll
        for (int i = 0; i < 4; ++i) { acur[i] = anxt[i]; bcur[i] = bnxt[i]; }
    }

    const int h = bn * 2 + wn;   // 64-col wave block == one head
    if (wsel <= 1) {             // fused RoPE: pair (d, d+32) = (nt, nt+2)
#pragma unroll
        for (int mt = 0; mt < 4; ++mt)
#pragma unroll
            for (int r = 0; r < 4; ++r) {
                int mg = bm * 128 + wm * 64 + mt * 16 + quad * 4 + r;
                int t  = mg & (Tn - 1);
#pragma unroll
                for (int nt = 0; nt < 2; ++nt) {
                    int d = nt * 16 + lx;   // 0..31
                    float ang = (float)t * __expf(-(float)d * 0.2878231366f);
                    float c, s;
                    __sincosf(ang, &s, &c);
                    float a0 = acc[mt][nt][r], a1 = acc[mt][nt + 2][r];
                    acc[mt][nt][r]     = a0 * c - a1 * s;
                    acc[mt][nt + 2][r] = a1 * c + a0 * s;
                }
            }
    }

#pragma unroll
    for (int mt = 0; mt < 4; ++mt) {
        int mg0 = bm * 128 + wm * 64 + mt * 16 + quad * 4;
        int b = mg0 >> 11, t0 = mg0 & (Tn - 1);
        if (wsel == 0) {        // Q: exp2-folded softmax scale
#pragma unroll
            for (int nt = 0; nt < 4; ++nt)
#pragma unroll
                for (int r = 0; r < 4; ++r) {
                    int d = nt * 16 + lx;
                    Qo[((size_t)(b * Hn + h) * Tn + t0 + r) * Dn + d] =
                        __float2bfloat16(acc[mt][nt][r] * QSCALE);
                }
        } else if (wsel == 1) { // K
#pragma unroll
            for (int nt = 0; nt < 4; ++nt)
#pragma unroll
                for (int r = 0; r < 4; ++r) {
                    int d = nt * 16 + lx;
                    Ko[((size_t)(b * Hn + h) * Tn + t0 + r) * Dn + d] =
                        __float2bfloat16(acc[mt][nt][r]);
                }
        } else {                // V^T [B,H,D,T]: r-contiguous -> 8B store
#pragma unroll
            for (int nt = 0; nt < 4; ++nt) {
                int d = nt * 16 + lx;
                short4v pk;
#pragma unroll
                for (int r = 0; r < 4; ++r) pk[r] = (short)bfbits(acc[mt][nt][r]);
                *(short4v*)&Vo[((size_t)(b * Hn + h) * Dn + d) * Tn + t0] = pk;
            }
        }
    }
}

// ---------------------------------------------------------------- out GEMM
// (round-9 proven) 128x64 tile (grid 32x16), BK=64, 4 waves 2x2, wave 64x32.
// A (row-major attention out) via LDS; B = Wo streamed from shuffled layout.
__global__ __launch_bounds__(256) void gemm_out_kernel(
    const bf16* __restrict__ A, const bf16* __restrict__ W, float* __restrict__ Out)
{
    __shared__ unsigned short As[128 * 64];
    const int bm = blockIdx.x, bn = blockIdx.y;
    const int tid  = threadIdx.x;
    const int wave = tid >> 6, lane = tid & 63;
    const int lx   = lane & 15, quad = lane >> 4;
    const int wm = wave >> 1, wn = wave & 1;

    const bf16* abase = A + (size_t)(bm * 128) * Cn;
    const int nb0 = bn * 4 + wn * 2;
    const bf16* wfrag = W + (size_t)nb0 * 32 * 512 + (size_t)lane * 8;

    f32x4 acc[4][2] = {};
    for (int kt = 0; kt < Cn / 64; ++kt) {
        __syncthreads();
        stage128(abase + kt * 64, Cn, As, wave, lane);
        bf16x8 bfv[2][2];
#pragma unroll
        for (int nt = 0; nt < 2; ++nt)
#pragma unroll
            for (int ks = 0; ks < 2; ++ks)
                bfv[nt][ks] = *(const bf16x8*)(wfrag +
                    ((size_t)nt * 32 + kt * 2 + ks) * 512);
        __syncthreads();
#pragma unroll
        for (int ks = 0; ks < 2; ++ks) {
            bf16x8 af[4];
#pragma unroll
            for (int mt = 0; mt < 4; ++mt)
                af[mt] = ldsfrag(As, wm * 64 + mt * 16 + lx, ks * 4 + quad);
#pragma unroll
            for (int mt = 0; mt < 4; ++mt)
#pragma unroll
                for (int nt = 0; nt < 2; ++nt)
                    acc[mt][nt] = MFMA16(af[mt], bfv[nt][ks], acc[mt][nt]);
        }
    }
#pragma unroll
    for (int mt = 0; mt < 4; ++mt)
#pragma unroll
        for (int nt = 0; nt < 2; ++nt)
#pragma unroll
            for (int r = 0; r < 4; ++r) {
                int mg = bm * 128 + wm * 64 + mt * 16 + quad * 4 + r;
                int ng = bn * 64 + wn * 32 + nt * 16 + lx;
                Out[(size_t)mg * Cn + ng] = acc[mt][nt][r];
            }
}

// ---------------------------------------------------------------- Attention
// (round-9/7 proven) 1024 blocks: f -> bh = (f&7)*4 + ((f>>3)&3),
// qb = 31 - (f>>5). One 64-row q-tile per block, 4 waves x 16 rows.
// K/V chunk LDS-staged (single-buffered). p = exp2(s), l via ones-MFMA.
__global__ __launch_bounds__(256) void attn_kernel(
    const bf16* __restrict__ Q, const bf16* __restrict__ K,
    const bf16* __restrict__ Vt, bf16* __restrict__ O)
{
    __shared__ unsigned short Ks[64 * 64];
    __shared__ unsigned short Vs[64 * 64];
    __shared__ unsigned short Pl[4][16 * 72];
    const int f  = blockIdx.x;
    const int bh = (f & 7) * 4 + ((f >> 3) & 3);
    const int qb = 31 - (f >> 5);
    const int tid  = threadIdx.x;
    const int wave = tid >> 6, lane = tid & 63;
    const int lx   = lane & 15, quad = lane >> 4;

    const bf16* Qh = Q  + (size_t)bh * Tn * Dn;
    const bf16* Kh = K  + (size_t)bh * Tn * Dn;
    const bf16* Vh = Vt + (size_t)bh * Dn * Tn;
    unsigned short* pw = &Pl[wave][0];

    const int qrowA = qb * 64 + wave * 16 + lx;   // A-frag m index
    bf16x8 aq0 = *(const bf16x8*)(Qh + (size_t)qrowA * Dn + quad * 8);
    bf16x8 aq1 = *(const bf16x8*)(Qh + (size_t)qrowA * Dn + 32 + quad * 8);

    bf16x8 ones;
#pragma unroll
    for (int i = 0; i < 8; ++i) ones[i] = (short)0x3F80;

    f32x4 acc_o[4] = {};
    f32x4 acc_l = {};
    const int row_local = wave * 16 + quad * 4;

    for (int c = 0; c <= qb; ++c) {
        __syncthreads();
        stage64(Kh + (size_t)c * 64 * Dn, Dn, Ks, wave, lane);
        stage64(Vh + (size_t)c * 64, Tn, Vs, wave, lane);
        __syncthreads();
        // ---- S = Q K^T (exp2 scale pre-folded into Q)
        f32x4 accs[4] = {};
#pragma unroll
        for (int nt = 0; nt < 4; ++nt) {
            int key = nt * 16 + lx;
            bf16x8 k0 = ldsfrag(Ks, key, quad);
            bf16x8 k1 = ldsfrag(Ks, key, quad + 4);
            accs[nt] = MFMA16(aq0, k0, accs[nt]);
            accs[nt] = MFMA16(aq1, k1, accs[nt]);
        }
        // ---- p = exp2(s) -> per-wave P buffer
        if (c < qb) {
#pragma unroll
            for (int nt = 0; nt < 4; ++nt)
#pragma unroll
                for (int r = 0; r < 4; ++r)
                    pw[(quad * 4 + r) * 72 + nt * 16 + lx] = bfbits(exp2f(accs[nt][r]));
        } else {   // diagonal chunk: causal mask
#pragma unroll
            for (int nt = 0; nt < 4; ++nt) {
                int keyl = nt * 16 + lx;
#pragma unroll
                for (int r = 0; r < 4; ++r) {
                    float p = (keyl > row_local + r) ? 0.0f : exp2f(accs[nt][r]);
                    pw[(quad * 4 + r) * 72 + nt * 16 + lx] = bfbits(p);
                }
            }
        }
        asm volatile("s_waitcnt lgkmcnt(0)" ::: "memory");
        bf16x8 ap0 = *(const bf16x8*)&pw[lx * 72 + quad * 8];
        bf16x8 ap1 = *(const bf16x8*)&pw[lx * 72 + 32 + quad * 8];
        // ---- l += P . 1
        acc_l = MFMA16(ap0, ones, acc_l);
        acc_l = MFMA16(ap1, ones, acc_l);
        // ---- O += P V
#pragma unroll
        for (int dt = 0; dt < 4; ++dt) {
            int d = dt * 16 + lx;
            bf16x8 v0 = ldsfrag(Vs, d, quad);
            bf16x8 v1 = ldsfrag(Vs, d, quad + 4);
            acc_o[dt] = MFMA16(ap0, v0, acc_o[dt]);
            acc_o[dt] = MFMA16(ap1, v1, acc_o[dt]);
        }
    }

    // epilogue: O[b,t,h,d] (= [B,T,C] row-major), bf16
    const int b = bh >> 4, h = bh & 15;
#pragma unroll
    for (int dt = 0; dt < 4; ++dt)
#pragma unroll
        for (int r = 0; r < 4; ++r) {
            int t = qb * 64 + row_local + r;
            int d = dt * 16 + lx;
            float o = acc_o[dt][r] / acc_l[r];
            O[((size_t)(b * Tn + t) * Hn + h) * Dn + d] = __float2bfloat16(o);
        }
}

// ---------------------------------------------------------------- launch
extern "C" void kernel_launch(void* const* d_in, const int* in_sizes, int n_in,
                              void* d_out, int out_size, void* d_ws, size_t ws_size,
                              hipStream_t stream)
{
    const float* x  = (const float*)d_in[0];
    const float* Wq = (const float*)d_in[1];
    const float* Wk = (const float*)d_in[2];
    const float* Wv = (const float*)d_in[3];
    const float* Wo = (const float*)d_in[4];
    float* out = (float*)d_out;

    bf16* ws = (bf16*)d_ws;
    bf16* Xf = ws;                    // x fragment-major (aliased by Ab after QKV)
    bf16* Wb = ws + NE;               // Wq,Wk,Wv,Wo bf16 SHUFFLED, contiguous
    bf16* Qb = ws + NE + 4 * WE;      // [B,H,T,D] (pre-scaled by 0.125*log2e)
    bf16* Kb = Qb + NE;               // [B,H,T,D]
    bf16* Vb = Kb + NE;               // [B,H,D,T]
    bf16* Ab = Xf;                    // attention out (row-major), reuses Xf

    convert_kernel<<<4096, 256, 0, stream>>>(x, Wq, Wk, Wv, Wo, ws);
    gemm_qkv_kernel<<<dim3(32, 8, 3), 256, 0, stream>>>(Xf, Wb, Qb, Kb, Vb);
    attn_kernel<<<1024, 256, 0, stream>>>(Qb, Kb, Vb, Ab);
    gemm_out_kernel<<<dim3(32, 16), 256, 0, stream>>>(Ab, Wb + 3 * WE, out);
}

// Round 12
// 176.154 us; speedup vs baseline: 1.0803x; 1.0057x over previous
//
#include <hip/hip_runtime.h>
#include <hip/hip_bf16.h>

// MultiHeadAttention fused pipeline. FP32 in/out, bf16 MFMA compute, fp32 accum.
// B=2 T=2048 C=1024 H=16 D=64.
// Stage 0: convert x AND W* -> bf16 SHUFFLED fragment-major layout
//          (frag f = (row>>4)*32 + (k>>5); elem f*512 + lane*8,
//           lane = ((k>>3)&3)*16 + (row&15)) -> wave fragment load = one
//          coalesced 1KB burst.
// Stage 1: QKV GEMM, ZERO-LDS / ZERO-BARRIER streaming (round-11 proven:
//          dropped below attn): A and B fragments global->VGPR with cur/next
//          prefetch, 16 MFMA per 32-k step. RoPE + exp2 scale in epilogue.
// Stage 2: attention (round-9/7 proven core): one 64-row q-tile per block,
//          1024 blocks, longest-first, XCD-swizzled bh, K/V LDS-staged,
//          p = exp2(s) no-max softmax, l via ones-MFMA, per-wave P.
//          Epilogue now writes O in FRAGMENT-MAJOR layout (same store count).
// Stage 3: out GEMM, ZERO-LDS / ZERO-BARRIER streaming like qkv: A from
//          fragment-major O, B from shuffled Wo -> fp32 d_out.
//
// MFMA layouts (HW-verified): A[m=lane&15][k=quad*8+j]; B[n=lane&15][k=quad*8+j];
// C/D: row=quad*4+reg, col=lane&15.
// LDS swizzle (attn staging): 16B chunk (row, ch) at row*8 + (ch^(row&7)).

typedef __hip_bfloat16 bf16;
typedef __attribute__((ext_vector_type(8))) short bf16x8;
typedef __attribute__((ext_vector_type(4))) float f32x4;
typedef __attribute__((ext_vector_type(4))) short short4v;

#define MFMA16(a, b, c) __builtin_amdgcn_mfma_f32_16x16x32_bf16((a), (b), (c), 0, 0, 0)

constexpr int Bn = 2, Hn = 16, Tn = 2048, Dn = 64, Cn = 1024;
constexpr size_t NE = (size_t)Bn * Tn * Cn;   // 4,194,304
constexpr size_t WE = (size_t)Cn * Cn;        // 1,048,576
// softmax scale 1/8 folded with log2(e): p = exp2(s) == exp(dot/8)
constexpr float QSCALE = 0.125f * 1.44269504088896f;

__device__ inline unsigned short bfbits(float x) {
    bf16 b = __float2bfloat16(x);
    return *(unsigned short*)&b;
}

__device__ inline bf16x8 pack8(f32x4 a, f32x4 b) {
    bf16x8 r;
#pragma unroll
    for (int i = 0; i < 4; ++i) r[i] = (short)bfbits(a[i]);
#pragma unroll
    for (int i = 0; i < 4; ++i) r[4 + i] = (short)bfbits(b[i]);
    return r;
}

__device__ inline void gl_lds16(const bf16* g, unsigned short* l) {
    __builtin_amdgcn_global_load_lds(
        (const __attribute__((address_space(1))) void*)g,
        (__attribute__((address_space(3))) void*)l, 16, 0, 0);
}

// stage a 64x64 tile (512 chunks), XOR-8 swizzle
__device__ inline void stage64(const bf16* gbase, int ld, unsigned short* lds,
                               int wave, int lane) {
#pragma unroll
    for (int j = 0; j < 2; ++j) {
        int p = j * 256 + wave * 64 + lane;
        int row = p >> 3, ch = (p & 7) ^ (row & 7);
        gl_lds16(gbase + (size_t)row * ld + ch * 8,
                 lds + (size_t)(j * 256 + wave * 64) * 8);
    }
}

__device__ inline bf16x8 ldsfrag(const unsigned short* base, int row, int ch) {
    return *(const bf16x8*)&base[row * 64 + ((ch ^ (row & 7)) * 8)];
}

// ---------------------------------------------------------------- convert
// blocks [0,2048): x -> fragment-major (256 m-tiles x 32 k-chunks).
// blocks [2048,4096): W* -> fragment-major (64 n-tiles x 32 k-chunks each).
__global__ __launch_bounds__(256) void convert_kernel(
    const float* __restrict__ x, const float* __restrict__ wq,
    const float* __restrict__ wk, const float* __restrict__ wv,
    const float* __restrict__ wo, bf16* __restrict__ dst)
{
    int blk = blockIdx.x;
    int lane = threadIdx.x & 63;
    int lx = lane & 15, quad = lane >> 4;
    const float* src;
    size_t doff;
    if (blk < 2048) {
        int frag = blk * 4 + (threadIdx.x >> 6);   // 0..8191
        int mt = frag >> 5, kc = frag & 31;
        src = x + (size_t)(mt * 16 + lx) * Cn + kc * 32 + quad * 8;
        doff = (size_t)frag * 512 + lane * 8;
    } else {
        int w = (blk - 2048) >> 9, b = (blk - 2048) & 511;
        const float* s4[4] = {wq, wk, wv, wo};
        int frag = b * 4 + (threadIdx.x >> 6);     // 0..2047
        int nb = frag >> 5, kc = frag & 31;
        src = s4[w] + (size_t)(nb * 16 + lx) * Cn + kc * 32 + quad * 8;
        doff = NE + (size_t)w * WE + (size_t)frag * 512 + lane * 8;
    }
    f32x4 a = *(const f32x4*)(src);
    f32x4 b2 = *(const f32x4*)(src + 4);
    *(bf16x8*)(dst + doff) = pack8(a, b2);
}

// ---------------------------------------------------------------- QKV GEMM
// ZERO-LDS streaming GEMM (round-11 proven): 4 waves (2x2), wave 64x64,
// K-step 32, cur/next prefetch, no barriers.
__global__ __launch_bounds__(256) void gemm_qkv_kernel(
    const bf16* __restrict__ Xf, const bf16* __restrict__ Wbase,
    bf16* __restrict__ Qo, bf16* __restrict__ Ko, bf16* __restrict__ Vo)
{
    const int bm = blockIdx.x, bn = blockIdx.y, wsel = blockIdx.z;
    const bf16* W = Wbase + (size_t)wsel * WE;
    const int tid  = threadIdx.x;
    const int wave = tid >> 6, lane = tid & 63;
    const int lx   = lane & 15, quad = lane >> 4;
    const int wm = wave >> 1, wn = wave & 1;

    const int mt0 = bm * 8 + wm * 4;               // first 16-row m-tile
    const int nb0 = bn * 8 + wn * 4;               // first 16-row n-tile
    const bf16* afrag = Xf + (size_t)mt0 * 32 * 512 + (size_t)lane * 8;
    const bf16* wfrag = W + (size_t)nb0 * 32 * 512 + (size_t)lane * 8;

    f32x4 acc[4][4] = {};   // [mt][nt]
    bf16x8 acur[4], bcur[4], anxt[4], bnxt[4];
#pragma unroll
    for (int i = 0; i < 4; ++i) {
        acur[i] = *(const bf16x8*)(afrag + (size_t)i * 32 * 512);
        bcur[i] = *(const bf16x8*)(wfrag + (size_t)i * 32 * 512);
    }
    for (int kc = 0; kc < 32; ++kc) {
        if (kc < 31) {   // prefetch next k-chunk while current MFMAs run
#pragma unroll
            for (int i = 0; i < 4; ++i) {
                anxt[i] = *(const bf16x8*)(afrag + ((size_t)i * 32 + kc + 1) * 512);
                bnxt[i] = *(const bf16x8*)(wfrag + ((size_t)i * 32 + kc + 1) * 512);
            }
        }
#pragma unroll
        for (int mt = 0; mt < 4; ++mt)
#pragma unroll
            for (int nt = 0; nt < 4; ++nt)
                acc[mt][nt] = MFMA16(acur[mt], bcur[nt], acc[mt][nt]);
#pragma unroll
        for (int i = 0; i < 4; ++i) { acur[i] = anxt[i]; bcur[i] = bnxt[i]; }
    }

    const int h = bn * 2 + wn;   // 64-col wave block == one head
    if (wsel <= 1) {             // fused RoPE: pair (d, d+32) = (nt, nt+2)
#pragma unroll
        for (int mt = 0; mt < 4; ++mt)
#pragma unroll
            for (int r = 0; r < 4; ++r) {
                int mg = bm * 128 + wm * 64 + mt * 16 + quad * 4 + r;
                int t  = mg & (Tn - 1);
#pragma unroll
                for (int nt = 0; nt < 2; ++nt) {
                    int d = nt * 16 + lx;   // 0..31
                    float ang = (float)t * __expf(-(float)d * 0.2878231366f);
                    float c, s;
                    __sincosf(ang, &s, &c);
                    float a0 = acc[mt][nt][r], a1 = acc[mt][nt + 2][r];
                    acc[mt][nt][r]     = a0 * c - a1 * s;
                    acc[mt][nt + 2][r] = a1 * c + a0 * s;
                }
            }
    }

#pragma unroll
    for (int mt = 0; mt < 4; ++mt) {
        int mg0 = bm * 128 + wm * 64 + mt * 16 + quad * 4;
        int b = mg0 >> 11, t0 = mg0 & (Tn - 1);
        if (wsel == 0) {        // Q: exp2-folded softmax scale
#pragma unroll
            for (int nt = 0; nt < 4; ++nt)
#pragma unroll
                for (int r = 0; r < 4; ++r) {
                    int d = nt * 16 + lx;
                    Qo[((size_t)(b * Hn + h) * Tn + t0 + r) * Dn + d] =
                        __float2bfloat16(acc[mt][nt][r] * QSCALE);
                }
        } else if (wsel == 1) { // K
#pragma unroll
            for (int nt = 0; nt < 4; ++nt)
#pragma unroll
                for (int r = 0; r < 4; ++r) {
                    int d = nt * 16 + lx;
                    Ko[((size_t)(b * Hn + h) * Tn + t0 + r) * Dn + d] =
                        __float2bfloat16(acc[mt][nt][r]);
                }
        } else {                // V^T [B,H,D,T]: r-contiguous -> 8B store
#pragma unroll
            for (int nt = 0; nt < 4; ++nt) {
                int d = nt * 16 + lx;
                short4v pk;
#pragma unroll
                for (int r = 0; r < 4; ++r) pk[r] = (short)bfbits(acc[mt][nt][r]);
                *(short4v*)&Vo[((size_t)(b * Hn + h) * Dn + d) * Tn + t0] = pk;
            }
        }
    }
}

// ---------------------------------------------------------------- out GEMM
// ZERO-LDS streaming GEMM: block 128x64, 4 waves (2x2), wave 64x32
// (4x2 accs), K-step 32, cur/next prefetch, no barriers. A from
// fragment-major attention output; B from shuffled Wo. fp32 row-major out.
__global__ __launch_bounds__(256) void gemm_out_kernel(
    const bf16* __restrict__ Af, const bf16* __restrict__ W, float* __restrict__ Out)
{
    const int bm = blockIdx.x, bn = blockIdx.y;
    const int tid  = threadIdx.x;
    const int wave = tid >> 6, lane = tid & 63;
    const int lx   = lane & 15, quad = lane >> 4;
    const int wm = wave >> 1, wn = wave & 1;

    const int mt0 = bm * 8 + wm * 4;
    const int nb0 = bn * 4 + wn * 2;
    const bf16* afrag = Af + (size_t)mt0 * 32 * 512 + (size_t)lane * 8;
    const bf16* wfrag = W + (size_t)nb0 * 32 * 512 + (size_t)lane * 8;

    f32x4 acc[4][2] = {};
    bf16x8 acur[4], bcur[2], anxt[4], bnxt[2];
#pragma unroll
    for (int i = 0; i < 4; ++i)
        acur[i] = *(const bf16x8*)(afrag + (size_t)i * 32 * 512);
#pragma unroll
    for (int i = 0; i < 2; ++i)
        bcur[i] = *(const bf16x8*)(wfrag + (size_t)i * 32 * 512);
    for (int kc = 0; kc < 32; ++kc) {
        if (kc < 31) {
#pragma unroll
            for (int i = 0; i < 4; ++i)
                anxt[i] = *(const bf16x8*)(afrag + ((size_t)i * 32 + kc + 1) * 512);
#pragma unroll
            for (int i = 0; i < 2; ++i)
                bnxt[i] = *(const bf16x8*)(wfrag + ((size_t)i * 32 + kc + 1) * 512);
        }
#pragma unroll
        for (int mt = 0; mt < 4; ++mt)
#pragma unroll
            for (int nt = 0; nt < 2; ++nt)
                acc[mt][nt] = MFMA16(acur[mt], bcur[nt], acc[mt][nt]);
#pragma unroll
        for (int i = 0; i < 4; ++i) acur[i] = anxt[i];
#pragma unroll
        for (int i = 0; i < 2; ++i) bcur[i] = bnxt[i];
    }
#pragma unroll
    for (int mt = 0; mt < 4; ++mt)
#pragma unroll
        for (int nt = 0; nt < 2; ++nt)
#pragma unroll
            for (int r = 0; r < 4; ++r) {
                int mg = bm * 128 + wm * 64 + mt * 16 + quad * 4 + r;
                int ng = bn * 64 + wn * 32 + nt * 16 + lx;
                Out[(size_t)mg * Cn + ng] = acc[mt][nt][r];
            }
}

// ---------------------------------------------------------------- Attention
// (round-9/7 proven core) 1024 blocks: f -> bh = (f&7)*4 + ((f>>3)&3),
// qb = 31 - (f>>5). One 64-row q-tile per block, 4 waves x 16 rows.
// K/V chunk LDS-staged. p = exp2(s), l via ones-MFMA.
// Epilogue writes O in FRAGMENT-MAJOR layout for the streaming out-GEMM:
//   global row g = b*2048 + t; ch = h*64 + d
//   frag = (g>>4)*32 + (ch>>5); lane = ((ch>>3)&3)*16 + (g&15); pos = ch&7
__global__ __launch_bounds__(256) void attn_kernel(
    const bf16* __restrict__ Q, const bf16* __restrict__ K,
    const bf16* __restrict__ Vt, bf16* __restrict__ O)
{
    __shared__ unsigned short Ks[64 * 64];
    __shared__ unsigned short Vs[64 * 64];
    __shared__ unsigned short Pl[4][16 * 72];
    const int f  = blockIdx.x;
    const int bh = (f & 7) * 4 + ((f >> 3) & 3);
    const int qb = 31 - (f >> 5);
    const int tid  = threadIdx.x;
    const int wave = tid >> 6, lane = tid & 63;
    const int lx   = lane & 15, quad = lane >> 4;

    const bf16* Qh = Q  + (size_t)bh * Tn * Dn;
    const bf16* Kh = K  + (size_t)bh * Tn * Dn;
    const bf16* Vh = Vt + (size_t)bh * Dn * Tn;
    unsigned short* pw = &Pl[wave][0];

    const int qrowA = qb * 64 + wave * 16 + lx;   // A-frag m index
    bf16x8 aq0 = *(const bf16x8*)(Qh + (size_t)qrowA * Dn + quad * 8);
    bf16x8 aq1 = *(const bf16x8*)(Qh + (size_t)qrowA * Dn + 32 + quad * 8);

    bf16x8 ones;
#pragma unroll
    for (int i = 0; i < 8; ++i) ones[i] = (short)0x3F80;

    f32x4 acc_o[4] = {};
    f32x4 acc_l = {};
    const int row_local = wave * 16 + quad * 4;

    for (int c = 0; c <= qb; ++c) {
        __syncthreads();
        stage64(Kh + (size_t)c * 64 * Dn, Dn, Ks, wave, lane);
        stage64(Vh + (size_t)c * 64, Tn, Vs, wave, lane);
        __syncthreads();
        // ---- S = Q K^T (exp2 scale pre-folded into Q)
        f32x4 accs[4] = {};
#pragma unroll
        for (int nt = 0; nt < 4; ++nt) {
            int key = nt * 16 + lx;
            bf16x8 k0 = ldsfrag(Ks, key, quad);
            bf16x8 k1 = ldsfrag(Ks, key, quad + 4);
            accs[nt] = MFMA16(aq0, k0, accs[nt]);
            accs[nt] = MFMA16(aq1, k1, accs[nt]);
        }
        // ---- p = exp2(s) -> per-wave P buffer
        if (c < qb) {
#pragma unroll
            for (int nt = 0; nt < 4; ++nt)
#pragma unroll
                for (int r = 0; r < 4; ++r)
                    pw[(quad * 4 + r) * 72 + nt * 16 + lx] = bfbits(exp2f(accs[nt][r]));
        } else {   // diagonal chunk: causal mask
#pragma unroll
            for (int nt = 0; nt < 4; ++nt) {
                int keyl = nt * 16 + lx;
#pragma unroll
                for (int r = 0; r < 4; ++r) {
                    float p = (keyl > row_local + r) ? 0.0f : exp2f(accs[nt][r]);
                    pw[(quad * 4 + r) * 72 + nt * 16 + lx] = bfbits(p);
                }
            }
        }
        asm volatile("s_waitcnt lgkmcnt(0)" ::: "memory");
        bf16x8 ap0 = *(const bf16x8*)&pw[lx * 72 + quad * 8];
        bf16x8 ap1 = *(const bf16x8*)&pw[lx * 72 + 32 + quad * 8];
        // ---- l += P . 1
        acc_l = MFMA16(ap0, ones, acc_l);
        acc_l = MFMA16(ap1, ones, acc_l);
        // ---- O += P V
#pragma unroll
        for (int dt = 0; dt < 4; ++dt) {
            int d = dt * 16 + lx;
            bf16x8 v0 = ldsfrag(Vs, d, quad);
            bf16x8 v1 = ldsfrag(Vs, d, quad + 4);
            acc_o[dt] = MFMA16(ap0, v0, acc_o[dt]);
            acc_o[dt] = MFMA16(ap1, v1, acc_o[dt]);
        }
    }

    // epilogue: fragment-major O write
    const int b = bh >> 4, h = bh & 15;
    // g>>4 = b*128 + qb*4 + wave  (constant per wave); g&15 = quad*4 + r
    const int mtile = b * 128 + qb * 4 + wave;
#pragma unroll
    for (int dt = 0; dt < 4; ++dt) {
        int ch = h * 64 + dt * 16 + lx;            // channel
        size_t base = ((size_t)mtile * 32 + (ch >> 5)) * 512
                    + (size_t)(((ch >> 3) & 3) * 16) * 8 + (ch & 7);
#pragma unroll
        for (int r = 0; r < 4; ++r) {
            float o = acc_o[dt][r] / acc_l[r];
            O[base + (size_t)(quad * 4 + r) * 8] = __float2bfloat16(o);
        }
    }
}

// ---------------------------------------------------------------- launch
extern "C" void kernel_launch(void* const* d_in, const int* in_sizes, int n_in,
                              void* d_out, int out_size, void* d_ws, size_t ws_size,
                              hipStream_t stream)
{
    const float* x  = (const float*)d_in[0];
    const float* Wq = (const float*)d_in[1];
    const float* Wk = (const float*)d_in[2];
    const float* Wv = (const float*)d_in[3];
    const float* Wo = (const float*)d_in[4];
    float* out = (float*)d_out;

    bf16* ws = (bf16*)d_ws;
    bf16* Xf = ws;                    // x fragment-major (aliased by Ab after QKV)
    bf16* Wb = ws + NE;               // Wq,Wk,Wv,Wo bf16 SHUFFLED, contiguous
    bf16* Qb = ws + NE + 4 * WE;      // [B,H,T,D] (pre-scaled by 0.125*log2e)
    bf16* Kb = Qb + NE;               // [B,H,T,D]
    bf16* Vb = Kb + NE;               // [B,H,D,T]
    bf16* Ab = Xf;                    // attention out FRAGMENT-MAJOR, reuses Xf

    convert_kernel<<<4096, 256, 0, stream>>>(x, Wq, Wk, Wv, Wo, ws);
    gemm_qkv_kernel<<<dim3(32, 8, 3), 256, 0, stream>>>(Xf, Wb, Qb, Kb, Vb);
    attn_kernel<<<1024, 256, 0, stream>>>(Qb, Kb, Vb, Ab);
    gemm_out_kernel<<<dim3(32, 16), 256, 0, stream>>>(Ab, Wb + 3 * WE, out);
}